// Round 2
// baseline (501.301 us; speedup 1.0000x reference)
//
#include <hip/hip_runtime.h>
#include <hip/hip_bf16.h>
#include <math.h>

// Problem constants (LightGFormer): B=16, N=512, D=256, L=4, H=8, dk=32, Dff=1024
#define BDIM 16
#define NSEQ 512
#define DMODEL 256
#define NLAYER 4
#define NHEAD 8
#define DK 32
#define DFF 1024
#define BN (BDIM * NSEQ)          // 8192 tokens
#define ND (NSEQ * DMODEL)        // 131072

typedef __bf16 bf16x8 __attribute__((ext_vector_type(8)));
typedef float floatx4 __attribute__((ext_vector_type(4)));
typedef unsigned uint32x2 __attribute__((ext_vector_type(2)));

// RNE float->bf16 bits
static __device__ __forceinline__ unsigned short f2bf(float f) {
    unsigned u = __float_as_uint(f);
    unsigned r = (u + 0x7FFFu + ((u >> 16) & 1u)) >> 16;
    return (unsigned short)r;
}

// async 16-byte global->LDS copy (wave-uniform LDS base + lane*16 required)
static __device__ __forceinline__ void async_ld16(const unsigned short* g,
                                                  unsigned short* l) {
    __builtin_amdgcn_global_load_lds(
        (const __attribute__((address_space(1))) unsigned int*)g,
        (__attribute__((address_space(3))) unsigned int*)l, 16, 0, 0);
}

// sigmoid-form tanh-approx GELU, |err| < 1e-3 vs exact
static __device__ __forceinline__ float gelu_f(float c) {
    float u = 0.7978845608028654f * (c + 0.044715f * c * c * c);
    return c * (1.f / (1.f + __expf(-2.f * u)));
}

// ---------------------------------------------------------------------------
// All weight conversions + mask pack in ONE dispatch.
// blocks [0,4096)  : Wq/Wk/Wv/Wo [L,K,N]->[L,N,K] bf16
// blocks [4096,8192): W1 [4,256,1024] -> w1T [4,1024,256]
// blocks [8192,9216): W2 [4,512,128]  -> w2T [4,128,512]
// blocks [9216,9248): mask -> bitmask (512 x 16 uint32); bit=1 -> -inf
// ---------------------------------------------------------------------------
__global__ void conv_all_kernel(const float* __restrict__ Wq, const float* __restrict__ Wk,
                                const float* __restrict__ Wv, const float* __restrict__ Wo,
                                const float* __restrict__ W1, const float* __restrict__ W2,
                                const int* __restrict__ mask,
                                unsigned short* __restrict__ wqT, unsigned short* __restrict__ wkT,
                                unsigned short* __restrict__ wvT, unsigned short* __restrict__ woT,
                                unsigned short* __restrict__ w1T, unsigned short* __restrict__ w2T,
                                unsigned* __restrict__ bits) {
    int blk = blockIdx.x, tid = threadIdx.x;
    if (blk < 4096) {
        int i = blk * 256 + tid;
        int sel = i >> 18;
        int j = i & 262143;
        int l = j >> 16, rem = j & 65535, kk = rem >> 8, n = rem & 255;
        const float* src = sel == 0 ? Wq : sel == 1 ? Wk : sel == 2 ? Wv : Wo;
        unsigned short* dst = sel == 0 ? wqT : sel == 1 ? wkT : sel == 2 ? wvT : woT;
        dst[(size_t)l * 65536 + n * 256 + kk] = f2bf(src[j]);
    } else if (blk < 8192) {
        int i = (blk - 4096) * 256 + tid;
        int l = i >> 18, rem = i & 262143, kk = rem >> 10, n = rem & 1023;
        w1T[(size_t)l * 262144 + (size_t)n * 256 + kk] = f2bf(W1[i]);
    } else if (blk < 9216) {
        int j = (blk - 8192) * 256 + tid;
        int l = j >> 16, rem = j & 65535, kk = rem >> 7, n = rem & 127;
        w2T[(size_t)l * 65536 + (size_t)n * 512 + kk] = f2bf(W2[j]);
    } else {
        int w = (blk - 9216) * 256 + tid;   // 0..8191
        int r = w >> 4, wi = w & 15;
        const int* src = mask + r * NSEQ + wi * 32;
        unsigned acc = 0;
#pragma unroll
        for (int j = 0; j < 32; j++) acc |= (src[j] != 0 ? 1u : 0u) << j;
        bits[w] = acc;
    }
}

// ---------------------------------------------------------------------------
// x = input + pos (fp32 + bf16) ; xv = input_v + pos (bf16 only)
// ---------------------------------------------------------------------------
__global__ void add_pos_kernel(const float* __restrict__ in,
                               const float* __restrict__ inv,
                               const float* __restrict__ pos,
                               float* __restrict__ x,
                               unsigned short* __restrict__ xb,
                               unsigned short* __restrict__ xvb,
                               int total) {
    int i = blockIdx.x * blockDim.x + threadIdx.x;
    if (i < total) {
        float pe = pos[i % ND];
        float a = in[i] + pe;
        float b = inv[i] + pe;
        x[i] = a;
        xb[i] = f2bf(a);
        xvb[i] = f2bf(b);
    }
}

// ---------------------------------------------------------------------------
// Fused QKV GEMM: grid (6, 64). blockIdx.x: 0,1->Q  2,3->K  4,5->V.
// Q output pre-scaled by 1/sqrt(dk) so attention skips the per-score scale.
// Output bf16 head-blocked: [(row/512)*8 + col/32][row%512][col%32]
// ---------------------------------------------------------------------------
__global__ __launch_bounds__(256) void qkv_mfma_kernel(
        const unsigned short* __restrict__ xb,
        const unsigned short* __restrict__ xvb,
        const unsigned short* __restrict__ WqT, const unsigned short* __restrict__ WkT,
        const unsigned short* __restrict__ WvT,
        const float* __restrict__ bq, const float* __restrict__ bk,
        const float* __restrict__ bv,
        unsigned short* __restrict__ qo, unsigned short* __restrict__ ko,
        unsigned short* __restrict__ vo) {
    int proj = blockIdx.x >> 1;
    const unsigned short* A  = (proj == 2) ? xvb : xb;
    const unsigned short* Bt = (proj == 0) ? WqT : (proj == 1) ? WkT : WvT;
    const float* bias        = (proj == 0) ? bq  : (proj == 1) ? bk  : bv;
    unsigned short* Cb       = (proj == 0) ? qo  : (proj == 1) ? ko  : vo;
    float qscale = (proj == 0) ? 0.17677669529663687f : 1.f;

    __shared__ unsigned short As[128 * 32];
    __shared__ unsigned short Bs[128 * 32];
    int tid = threadIdx.x;
    int wave = tid >> 6, lane = tid & 63;
    int rowBase = blockIdx.y * 128, colBase = (blockIdx.x & 1) * 128;
    int m0w = (wave & 1) * 64, n0w = (wave >> 1) * 64;
    int lr = lane & 15, quad = lane >> 4;

    floatx4 acc[4][4];
#pragma unroll
    for (int mi = 0; mi < 4; mi++)
#pragma unroll
        for (int nj = 0; nj < 4; nj++) acc[mi][nj] = (floatx4)0.0f;

    for (int kt = 0; kt < DMODEL; kt += 32) {
#pragma unroll
        for (int t = 0; t < 2; t++) {
            int idx = t * 256 + tid;
            int row = idx >> 2, kv8 = (idx & 3) * 8;
            async_ld16(A + (size_t)(rowBase + row) * DMODEL + kt + kv8, &As[idx * 8]);
            async_ld16(Bt + (size_t)(colBase + row) * DMODEL + kt + kv8, &Bs[idx * 8]);
        }
        __syncthreads();
        bf16x8 af[4], bfr[4];
#pragma unroll
        for (int mi = 0; mi < 4; mi++)
            af[mi] = *(const bf16x8*)&As[(m0w + mi * 16 + lr) * 32 + quad * 8];
#pragma unroll
        for (int nj = 0; nj < 4; nj++)
            bfr[nj] = *(const bf16x8*)&Bs[(n0w + nj * 16 + lr) * 32 + quad * 8];
#pragma unroll
        for (int mi = 0; mi < 4; mi++)
#pragma unroll
            for (int nj = 0; nj < 4; nj++)
                acc[mi][nj] = __builtin_amdgcn_mfma_f32_16x16x32_bf16(
                    af[mi], bfr[nj], acc[mi][nj], 0, 0, 0);
        __syncthreads();
    }

#pragma unroll
    for (int mi = 0; mi < 4; mi++) {
#pragma unroll
        for (int r = 0; r < 4; r++) {
            int grow = rowBase + m0w + mi * 16 + quad * 4 + r;
#pragma unroll
            for (int nj = 0; nj < 4; nj++) {
                int gcol = colBase + n0w + nj * 16 + lr;
                float c = (acc[mi][nj][r] + bias[gcol]) * qscale;
                size_t off = ((size_t)((grow >> 9) * 8 + (gcol >> 5)) << 14)
                           + (size_t)(grow & 511) * 32 + (gcol & 31);
                Cb[off] = f2bf(c);
            }
        }
    }
}

// ---------------------------------------------------------------------------
// Generic MFMA GEMM (FFN1): C = A @ Bt^T + bias, optional GELU, bf16 out.
// ---------------------------------------------------------------------------
__global__ __launch_bounds__(256) void gemm_mfma_kernel(
        const unsigned short* __restrict__ A,
        const unsigned short* __restrict__ Bt,
        const float* __restrict__ bias,
        unsigned short* __restrict__ Cb,
        int M, int K, int N, int act) {
    __shared__ unsigned short As[128 * 32];
    __shared__ unsigned short Bs[128 * 32];
    int tid = threadIdx.x;
    int wave = tid >> 6, lane = tid & 63;
    int rowBase = blockIdx.y * 128, colBase = blockIdx.x * 128;
    int m0w = (wave & 1) * 64, n0w = (wave >> 1) * 64;
    int lr = lane & 15, quad = lane >> 4;

    floatx4 acc[4][4];
#pragma unroll
    for (int mi = 0; mi < 4; mi++)
#pragma unroll
        for (int nj = 0; nj < 4; nj++) acc[mi][nj] = (floatx4)0.0f;

    for (int kt = 0; kt < K; kt += 32) {
#pragma unroll
        for (int t = 0; t < 2; t++) {
            int idx = t * 256 + tid;
            int row = idx >> 2, kv8 = (idx & 3) * 8;
            async_ld16(A + (size_t)(rowBase + row) * K + kt + kv8, &As[idx * 8]);
            async_ld16(Bt + (size_t)(colBase + row) * K + kt + kv8, &Bs[idx * 8]);
        }
        __syncthreads();
        bf16x8 af[4], bfr[4];
#pragma unroll
        for (int mi = 0; mi < 4; mi++)
            af[mi] = *(const bf16x8*)&As[(m0w + mi * 16 + lr) * 32 + quad * 8];
#pragma unroll
        for (int nj = 0; nj < 4; nj++)
            bfr[nj] = *(const bf16x8*)&Bs[(n0w + nj * 16 + lr) * 32 + quad * 8];
#pragma unroll
        for (int mi = 0; mi < 4; mi++)
#pragma unroll
            for (int nj = 0; nj < 4; nj++)
                acc[mi][nj] = __builtin_amdgcn_mfma_f32_16x16x32_bf16(
                    af[mi], bfr[nj], acc[mi][nj], 0, 0, 0);
        __syncthreads();
    }

#pragma unroll
    for (int mi = 0; mi < 4; mi++) {
#pragma unroll
        for (int r = 0; r < 4; r++) {
            int grow = rowBase + m0w + mi * 16 + quad * 4 + r;
#pragma unroll
            for (int nj = 0; nj < 4; nj++) {
                int gcol = colBase + n0w + nj * 16 + lr;
                float c = acc[mi][nj][r] + bias[gcol];
                if (act) c = gelu_f(c);
                Cb[(size_t)grow * N + gcol] = f2bf(c);
            }
        }
    }
}

// ---------------------------------------------------------------------------
// Fused Wo-GEMM + bias + residual + LayerNorm.
// 16 rows x 256 cols per block, ONE wave (64 thr), grid 512 -> 2 blocks/CU
// so staging latency of independent blocks overlaps (was 1 block/CU).
// ---------------------------------------------------------------------------
__global__ __launch_bounds__(64) void wo_ln_kernel(
        const unsigned short* __restrict__ A,     // ab_b [8192][256]
        const unsigned short* __restrict__ Bt,    // woT [256][256]
        const float* __restrict__ bias,
        const float* __restrict__ g, const float* __restrict__ be,
        float* __restrict__ xf, unsigned short* __restrict__ xb) {
    __shared__ unsigned short As[16 * 32];
    __shared__ unsigned short Bs[256 * 32];
    int tid = threadIdx.x;
    int l16 = tid & 15, quad = tid >> 4;
    int rowBase = blockIdx.x * 16;

    floatx4 acc[16];
#pragma unroll
    for (int t = 0; t < 16; t++) acc[t] = (floatx4)0.0f;

    for (int kt = 0; kt < 256; kt += 32) {
        {
            int row = tid >> 2, kv8 = (tid & 3) * 8;
            async_ld16(A + (size_t)(rowBase + row) * 256 + kt + kv8, &As[tid * 8]);
        }
#pragma unroll
        for (int t = 0; t < 16; t++) {
            int idx = t * 64 + tid;
            int row = idx >> 2, kv8 = (idx & 3) * 8;
            async_ld16(Bt + (size_t)row * 256 + kt + kv8, &Bs[idx * 8]);
        }
        __syncthreads();
        bf16x8 af = *(const bf16x8*)&As[l16 * 32 + quad * 8];
#pragma unroll
        for (int t = 0; t < 16; t++) {
            bf16x8 bfr = *(const bf16x8*)&Bs[(t * 16 + l16) * 32 + quad * 8];
            acc[t] = __builtin_amdgcn_mfma_f32_16x16x32_bf16(af, bfr, acc[t], 0, 0, 0);
        }
        __syncthreads();
    }

    float bcol[16], gc[16], bec[16];
#pragma unroll
    for (int t = 0; t < 16; t++) {
        int c = t * 16 + l16;
        bcol[t] = bias[c]; gc[t] = g[c]; bec[t] = be[c];
    }
#pragma unroll
    for (int r = 0; r < 4; r++) {
        int grow = rowBase + quad * 4 + r;
        float v[16], s = 0.f, s2 = 0.f;
#pragma unroll
        for (int t = 0; t < 16; t++) {
            int c = t * 16 + l16;
            float val = acc[t][r] + bcol[t] + xf[(size_t)grow * 256 + c];
            v[t] = val; s += val; s2 += val * val;
        }
#pragma unroll
        for (int off = 1; off <= 8; off <<= 1) {
            s += __shfl_xor(s, off);
            s2 += __shfl_xor(s2, off);
        }
        float mean = s * (1.f / 256.f);
        float var = s2 * (1.f / 256.f) - mean * mean;
        float rstd = rsqrtf(var + 1e-5f);
#pragma unroll
        for (int t = 0; t < 16; t++) {
            int c = t * 16 + l16;
            float o = (v[t] - mean) * rstd * gc[t] + bec[t];
            xf[(size_t)grow * 256 + c] = o;
            xb[(size_t)grow * 256 + c] = f2bf(o);
        }
    }
}

// ---------------------------------------------------------------------------
// Fused FFN2(grouped) + bias + residual + LayerNorm. 64 rows x 128 cols.
// ---------------------------------------------------------------------------
__global__ __launch_bounds__(128) void ffn2_ln_kernel(
        const unsigned short* __restrict__ A,     // h_b [16384][512]
        const unsigned short* __restrict__ Bt,    // w2T [128][512]
        const float* __restrict__ bias,           // [128]
        const float* __restrict__ g, const float* __restrict__ be,
        float* __restrict__ xf, unsigned short* __restrict__ xb) {
    __shared__ unsigned short As[64 * 32];
    __shared__ unsigned short Bs[128 * 32];
    __shared__ float redS[64][2], redQ[64][2];
    int tid = threadIdx.x;
    int wave = tid >> 6, lane = tid & 63, l16 = lane & 15, quad = lane >> 4;
    int rowBase = blockIdx.x * 64;
    int n0w = wave * 64;

    floatx4 acc[4][4];
#pragma unroll
    for (int mi = 0; mi < 4; mi++)
#pragma unroll
        for (int nj = 0; nj < 4; nj++) acc[mi][nj] = (floatx4)0.0f;

    for (int kt = 0; kt < 512; kt += 32) {
#pragma unroll
        for (int t = 0; t < 2; t++) {
            int idx = t * 128 + tid;
            int row = idx >> 2, kv8 = (idx & 3) * 8;
            async_ld16(A + (size_t)(rowBase + row) * 512 + kt + kv8, &As[idx * 8]);
        }
#pragma unroll
        for (int t = 0; t < 4; t++) {
            int idx = t * 128 + tid;
            int row = idx >> 2, kv8 = (idx & 3) * 8;
            async_ld16(Bt + (size_t)row * 512 + kt + kv8, &Bs[idx * 8]);
        }
        __syncthreads();
        bf16x8 af[4], bfr[4];
#pragma unroll
        for (int mi = 0; mi < 4; mi++)
            af[mi] = *(const bf16x8*)&As[(mi * 16 + l16) * 32 + quad * 8];
#pragma unroll
        for (int nj = 0; nj < 4; nj++)
            bfr[nj] = *(const bf16x8*)&Bs[(n0w + nj * 16 + l16) * 32 + quad * 8];
#pragma unroll
        for (int mi = 0; mi < 4; mi++)
#pragma unroll
            for (int nj = 0; nj < 4; nj++)
                acc[mi][nj] = __builtin_amdgcn_mfma_f32_16x16x32_bf16(
                    af[mi], bfr[nj], acc[mi][nj], 0, 0, 0);
        __syncthreads();
    }

#pragma unroll
    for (int mi = 0; mi < 4; mi++) {
#pragma unroll
        for (int r = 0; r < 4; r++) {
            int row = mi * 16 + quad * 4 + r;       // 0..63
            int grow = rowBase + row;
            int token = grow >> 1, dbase = (grow & 1) * 128;
            float s = 0.f, s2 = 0.f;
#pragma unroll
            for (int nj = 0; nj < 4; nj++) {
                int gcol = n0w + nj * 16 + l16;
                float val = acc[mi][nj][r] + bias[gcol]
                          + xf[(size_t)token * 256 + dbase + gcol];
                acc[mi][nj][r] = val;
                s += val; s2 += val * val;
            }
#pragma unroll
            for (int off = 1; off <= 8; off <<= 1) {
                s += __shfl_xor(s, off);
                s2 += __shfl_xor(s2, off);
            }
            if (l16 == 0) { redS[row][wave] = s; redQ[row][wave] = s2; }
        }
    }
    __syncthreads();

#pragma unroll
    for (int mi = 0; mi < 4; mi++) {
#pragma unroll
        for (int r = 0; r < 4; r++) {
            int row = mi * 16 + quad * 4 + r;
            int grow = rowBase + row;
            int token = grow >> 1, dbase = (grow & 1) * 128;
            float ts = redS[row][0] + redS[row][1] + redS[row ^ 1][0] + redS[row ^ 1][1];
            float tq = redQ[row][0] + redQ[row][1] + redQ[row ^ 1][0] + redQ[row ^ 1][1];
            float mean = ts * (1.f / 256.f);
            float var = tq * (1.f / 256.f) - mean * mean;
            float rstd = rsqrtf(var + 1e-5f);
#pragma unroll
            for (int nj = 0; nj < 4; nj++) {
                int gcol = n0w + nj * 16 + l16;
                int d = dbase + gcol;
                float o = (acc[mi][nj][r] - mean) * rstd * g[d] + be[d];
                xf[(size_t)token * 256 + d] = o;
                xb[(size_t)token * 256 + d] = f2bf(o);
            }
        }
    }
}

// ---------------------------------------------------------------------------
// MFMA attention. Grid = B*H*8 q-groups of 64.
// V staged via global_load_lds into two d-block-major halves
//   Vs[db][k*16+d] = V[k][db*16+d]
// and consumed with ds_read_b64_tr_b16 (HW 4x16 transpose):
//   per-lane addr = base + lane*8; 16-lane group q covers elems [64q,64q+63];
//   lane (q,l16) elem j = elem 64q+16j+l16 -> V[kkb + 4*quad + j][db*16 + l16]
//   == exactly the PV A-fragment the proven Vt-gather produced.
// Q arrives pre-scaled by 1/sqrt(dk) from qkv_mfma_kernel.
// ---------------------------------------------------------------------------
__global__ __launch_bounds__(256) void attn_mfma_kernel(
        const unsigned short* __restrict__ q, const unsigned short* __restrict__ k,
        const unsigned short* __restrict__ v, unsigned short* __restrict__ o,
        const unsigned* __restrict__ mbits_g, int use_mask) {
    int bid = blockIdx.x;
    int qg = bid & 7, h = (bid >> 3) & 7, b = bid >> 6;
    int tid = threadIdx.x;

    __shared__ unsigned short Ks[NSEQ * DK];        // 32KB  [k][32]
    __shared__ unsigned short Vs[2][NSEQ * 16];     // 32KB  [db][k*16+d]

    const unsigned short* kbase = k + (size_t)(b * 8 + h) * (NSEQ * DK);
    const unsigned short* vbase = v + (size_t)(b * 8 + h) * (NSEQ * DK);

#pragma unroll
    for (int t = 0; t < 8; t++) {
        int idx = t * 256 + tid;
        async_ld16(kbase + (size_t)idx * 8, &Ks[idx * 8]);
    }
    // V split: chunk c (16B) of Vs[db] covers k=c>>1, d = db*16 + (c&1)*8 .. +7
#pragma unroll
    for (int db = 0; db < 2; db++) {
#pragma unroll
        for (int t = 0; t < 4; t++) {
            int c = t * 256 + tid;                  // 0..1023
            int kk = c >> 1, half = c & 1;
            async_ld16(vbase + (size_t)kk * 32 + db * 16 + half * 8,
                       &Vs[db][c * 8]);
        }
    }

    int wave = tid >> 6, lane = tid & 63, l16 = lane & 15, quad = lane >> 4;
    int qbase = qg * 64 + wave * 16;

    bf16x8 qf = *(const bf16x8*)(q + ((size_t)(b * 8 + h) * NSEQ + qbase + l16) * 32 + quad * 8);

    unsigned mw[16];
    if (use_mask) {
        const uint4* mr = (const uint4*)(mbits_g + (size_t)(qbase + l16) * 16);
#pragma unroll
        for (int w = 0; w < 4; w++) *(uint4*)&mw[w * 4] = mr[w];
    } else {
#pragma unroll
        for (int w = 0; w < 16; w++) mw[w] = 0;
    }
    __syncthreads();

    unsigned va0 = (unsigned)(size_t)&Vs[0][0] + (unsigned)(lane * 8);
    unsigned va1 = (unsigned)(size_t)&Vs[1][0] + (unsigned)(lane * 8);

    floatx4 oT0 = (floatx4)0.f, oT1 = (floatx4)0.f;
    float m_run = -INFINITY, l_part = 0.f;

#pragma unroll
    for (int c = 0; c < 16; c++) {
        int kkb = c * 32;
        bf16x8 k0 = *(const bf16x8*)&Ks[(kkb + l16) * 32 + quad * 8];
        bf16x8 k1 = *(const bf16x8*)&Ks[(kkb + 16 + l16) * 32 + quad * 8];
        floatx4 s0 = __builtin_amdgcn_mfma_f32_16x16x32_bf16(k0, qf, (floatx4)0.f, 0, 0, 0);
        floatx4 s1 = __builtin_amdgcn_mfma_f32_16x16x32_bf16(k1, qf, (floatx4)0.f, 0, 0, 0);

        float sv[8];
#pragma unroll
        for (int r = 0; r < 4; r++) { sv[r] = s0[r]; sv[4 + r] = s1[r]; }
        if (use_mask) {
            unsigned wb = mw[c];
#pragma unroll
            for (int r = 0; r < 4; r++) {
                if ((wb >> (quad * 4 + r)) & 1) sv[r] = -INFINITY;
                if ((wb >> (16 + quad * 4 + r)) & 1) sv[4 + r] = -INFINITY;
            }
        }
        float mx = fmaxf(fmaxf(fmaxf(sv[0], sv[1]), fmaxf(sv[2], sv[3])),
                         fmaxf(fmaxf(sv[4], sv[5]), fmaxf(sv[6], sv[7])));
        mx = fmaxf(mx, __shfl_xor(mx, 16));
        mx = fmaxf(mx, __shfl_xor(mx, 32));
        // wave-uniform exact skip: if no lane's block-max exceeds the running
        // max, mnew == m_run for every lane and the rescale is a no-op.
        if (!__all(mx <= m_run)) {
            float mnew = fmaxf(m_run, mx);
            float corr = (m_run == mnew) ? 1.f : __expf(m_run - mnew);
            l_part *= corr;
            oT0 *= corr; oT1 *= corr;
            m_run = mnew;
        }
        float p[8];
#pragma unroll
        for (int j = 0; j < 8; j++) {
            float e = __expf(sv[j] - m_run);
            p[j] = (sv[j] > -INFINITY) ? e : 0.f;
            l_part += p[j];
        }
        union { bf16x8 v8; unsigned u[4]; } pf;
#pragma unroll
        for (int j = 0; j < 4; j++)
            asm("v_cvt_pk_bf16_f32 %0, %1, %2"
                : "=v"(pf.u[j]) : "v"(p[2 * j]), "v"(p[2 * j + 1]));

        uint32x2 t00, t01, t10, t11;
        unsigned a0 = va0 + (unsigned)(c * 1024);
        unsigned a1 = va1 + (unsigned)(c * 1024);
        asm volatile("ds_read_b64_tr_b16 %0, %4\n\t"
                     "ds_read_b64_tr_b16 %1, %4 offset:512\n\t"
                     "ds_read_b64_tr_b16 %2, %5\n\t"
                     "ds_read_b64_tr_b16 %3, %5 offset:512\n\t"
                     "s_waitcnt lgkmcnt(0)"
                     : "=&v"(t00), "=&v"(t01), "=&v"(t10), "=&v"(t11)
                     : "v"(a0), "v"(a1));
        __builtin_amdgcn_sched_barrier(0);
        union { bf16x8 v8; uint32x2 u[2]; } av0, av1;
        av0.u[0] = t00; av0.u[1] = t01;
        av1.u[0] = t10; av1.u[1] = t11;

        oT0 = __builtin_amdgcn_mfma_f32_16x16x32_bf16(av0.v8, pf.v8, oT0, 0, 0, 0);
        oT1 = __builtin_amdgcn_mfma_f32_16x16x32_bf16(av1.v8, pf.v8, oT1, 0, 0, 0);
    }

    float l = l_part;
    l += __shfl_xor(l, 16);
    l += __shfl_xor(l, 32);
    float invl = (l > 0.f) ? 1.f / l : 0.f;

    unsigned short* orow = o + ((size_t)(b * NSEQ + qbase + l16)) * DMODEL + h * DK;
#pragma unroll
    for (int r = 0; r < 4; r++) {
        orow[quad * 4 + r]      = f2bf(oT0[r] * invl);
        orow[16 + quad * 4 + r] = f2bf(oT1[r] * invl);
    }
}

// Final LN: out = LayerNorm(x) * gf + bf (fp32)
__global__ __launch_bounds__(256) void final_ln_kernel(
        const float* __restrict__ a,
        const float* __restrict__ g, const float* __restrict__ be,
        float* __restrict__ out) {
    int t = blockIdx.x;
    int d = threadIdx.x;
    size_t idx = (size_t)t * DMODEL + d;
    float v = a[idx];
    float s = v, s2 = v * v;
#pragma unroll
    for (int off = 32; off; off >>= 1) {
        s  += __shfl_xor(s, off);
        s2 += __shfl_xor(s2, off);
    }
    __shared__ float ws1[4], ws2[4];
    int wid = d >> 6;
    if ((d & 63) == 0) { ws1[wid] = s; ws2[wid] = s2; }
    __syncthreads();
    s  = ws1[0] + ws1[1] + ws1[2] + ws1[3];
    s2 = ws2[0] + ws2[1] + ws2[2] + ws2[3];
    float mean = s * (1.f / DMODEL);
    float var = s2 * (1.f / DMODEL) - mean * mean;
    float rstd = rsqrtf(var + 1e-5f);
    out[idx] = (v - mean) * rstd * g[d] + be[d];
}

// ---------------------------------------------------------------------------
extern "C" void kernel_launch(void* const* d_in, const int* in_sizes, int n_in,
                              void* d_out, int out_size, void* d_ws, size_t ws_size,
                              hipStream_t stream) {
    const float* input  = (const float*)d_in[0];
    const float* inputv = (const float*)d_in[1];
    const float* pos    = (const float*)d_in[2];
    const float* Wq = (const float*)d_in[3];
    const float* bq = (const float*)d_in[4];
    const float* Wk = (const float*)d_in[5];
    const float* bk = (const float*)d_in[6];
    const float* Wv = (const float*)d_in[7];
    const float* bv = (const float*)d_in[8];
    const float* Wo = (const float*)d_in[9];
    const float* bo = (const float*)d_in[10];
    const float* W1 = (const float*)d_in[11];
    const float* b1 = (const float*)d_in[12];
    const float* W2 = (const float*)d_in[13];
    const float* b2 = (const float*)d_in[14];
    const float* g1 = (const float*)d_in[15];
    const float* be1 = (const float*)d_in[16];
    const float* g2 = (const float*)d_in[17];
    const float* be2 = (const float*)d_in[18];
    const float* gf = (const float*)d_in[19];
    const float* bff = (const float*)d_in[20];
    const int* mask = (const int*)d_in[21];

    float* out = (float*)d_out;

    // Workspace layout (bytes), ~37 MB
    char* wsb = (char*)d_ws;
    float* x_f  = (float*)(wsb + ((size_t)0 << 20));                    // 8 MB
    unsigned short* x_b  = (unsigned short*)(wsb + ((size_t)8 << 20));  // 4 MB
    unsigned short* xv_b = (unsigned short*)(wsb + ((size_t)12 << 20)); // 4 MB
    unsigned short* qb_b = (unsigned short*)(wsb + ((size_t)16 << 20)); // 4 MB
    unsigned short* kb_b = (unsigned short*)(wsb + ((size_t)20 << 20)); // 4 MB
    unsigned short* vb_b = (unsigned short*)(wsb + ((size_t)24 << 20)); // 4 MB
    unsigned short* ab_b = (unsigned short*)(wsb + ((size_t)28 << 20)); // 4 MB
    unsigned short* h_b  = qb_b;  // 16 MB alias over qb..ab (dead during FFN)
    unsigned short* wqT = (unsigned short*)(wsb + ((size_t)32 << 20));
    unsigned short* wkT = wqT + (size_t)4 * 65536;
    unsigned short* wvT = wkT + (size_t)4 * 65536;
    unsigned short* woT = wvT + (size_t)4 * 65536;
    unsigned short* w1T = woT + (size_t)4 * 65536;   // 4 x 262144
    unsigned short* w2T = w1T + (size_t)4 * 262144;  // 4 x 65536
    unsigned* mbits = (unsigned*)(wsb + ((size_t)37 << 20));            // 32 KB

    const size_t TOK = (size_t)BN * DMODEL;

    // --- preconversions (2 dispatches) ---
    conv_all_kernel<<<9248, 256, 0, stream>>>(Wq, Wk, Wv, Wo, W1, W2, mask,
                                              wqT, wkT, wvT, woT, w1T, w2T, mbits);
    add_pos_kernel<<<(int)((TOK + 255) / 256), 256, 0, stream>>>(
        input, inputv, pos, x_f, x_b, xv_b, (int)TOK);

    for (int i = 0; i < NLAYER; i++) {
        const unsigned short* WqT_i = wqT + (size_t)i * 65536;
        const unsigned short* WkT_i = wkT + (size_t)i * 65536;
        const unsigned short* WvT_i = wvT + (size_t)i * 65536;
        const unsigned short* WoT_i = woT + (size_t)i * 65536;
        const unsigned short* W1T_i = w1T + (size_t)i * 262144;
        const unsigned short* W2T_i = w2T + (size_t)i * 65536;

        qkv_mfma_kernel<<<dim3(6, 64), 256, 0, stream>>>(
            x_b, xv_b, WqT_i, WkT_i, WvT_i,
            bq + i * DMODEL, bk + i * DMODEL, bv + i * DMODEL,
            qb_b, kb_b, vb_b);

        attn_mfma_kernel<<<BDIM * NHEAD * 8, 256, 0, stream>>>(
            qb_b, kb_b, vb_b, ab_b, mbits, (i & 1));

        wo_ln_kernel<<<BN / 16, 64, 0, stream>>>(
            ab_b, WoT_i, bo + i * DMODEL,
            g1 + i * DMODEL, be1 + i * DMODEL, x_f, x_b);

        gemm_mfma_kernel<<<dim3(8, 64), 256, 0, stream>>>(
            x_b, W1T_i, b1 + i * DFF, h_b, BN, DMODEL, DFF, 1);

        ffn2_ln_kernel<<<(2 * BN) / 64, 128, 0, stream>>>(
            h_b, W2T_i, b2 + i * (DMODEL / 2),
            g2 + i * DMODEL, be2 + i * DMODEL, x_f, x_b);
    }

    final_ln_kernel<<<BN, DMODEL, 0, stream>>>(x_f, gf, bff, out);
}

// Round 3
// 461.840 us; speedup vs baseline: 1.0854x; 1.0854x over previous
//
#include <hip/hip_runtime.h>
#include <hip/hip_bf16.h>
#include <math.h>

// Problem constants (LightGFormer): B=16, N=512, D=256, L=4, H=8, dk=32, Dff=1024
#define BDIM 16
#define NSEQ 512
#define DMODEL 256
#define NLAYER 4
#define NHEAD 8
#define DK 32
#define DFF 1024
#define BN (BDIM * NSEQ)          // 8192 tokens
#define ND (NSEQ * DMODEL)        // 131072

typedef __bf16 bf16x8 __attribute__((ext_vector_type(8)));
typedef float floatx4 __attribute__((ext_vector_type(4)));
typedef unsigned uint32x2 __attribute__((ext_vector_type(2)));

// RNE float->bf16 bits
static __device__ __forceinline__ unsigned short f2bf(float f) {
    unsigned u = __float_as_uint(f);
    unsigned r = (u + 0x7FFFu + ((u >> 16) & 1u)) >> 16;
    return (unsigned short)r;
}

// async 16-byte global->LDS copy (wave-uniform LDS base + lane*16 required)
static __device__ __forceinline__ void async_ld16(const unsigned short* g,
                                                  unsigned short* l) {
    __builtin_amdgcn_global_load_lds(
        (const __attribute__((address_space(1))) unsigned int*)g,
        (__attribute__((address_space(3))) unsigned int*)l, 16, 0, 0);
}

// sigmoid-form tanh-approx GELU, |err| < 1e-3 vs exact
static __device__ __forceinline__ float gelu_f(float c) {
    float u = 0.7978845608028654f * (c + 0.044715f * c * c * c);
    return c * (1.f / (1.f + __expf(-2.f * u)));
}

// ---------------------------------------------------------------------------
// All weight conversions + mask pack in ONE dispatch.
// blocks [0,4096)  : Wq/Wk/Wv/Wo [L,K,N]->[L,N,K] bf16
// blocks [4096,8192): W1 [4,256,1024] -> w1T [4,1024,256]
// blocks [8192,9216): W2 [4,512,128]  -> w2T [4,128,512]
// blocks [9216,9248): mask -> bitmask (512 x 16 uint32); bit=1 -> -inf
// ---------------------------------------------------------------------------
__global__ void conv_all_kernel(const float* __restrict__ Wq, const float* __restrict__ Wk,
                                const float* __restrict__ Wv, const float* __restrict__ Wo,
                                const float* __restrict__ W1, const float* __restrict__ W2,
                                const int* __restrict__ mask,
                                unsigned short* __restrict__ wqT, unsigned short* __restrict__ wkT,
                                unsigned short* __restrict__ wvT, unsigned short* __restrict__ woT,
                                unsigned short* __restrict__ w1T, unsigned short* __restrict__ w2T,
                                unsigned* __restrict__ bits) {
    int blk = blockIdx.x, tid = threadIdx.x;
    if (blk < 4096) {
        int i = blk * 256 + tid;
        int sel = i >> 18;
        int j = i & 262143;
        int l = j >> 16, rem = j & 65535, kk = rem >> 8, n = rem & 255;
        const float* src = sel == 0 ? Wq : sel == 1 ? Wk : sel == 2 ? Wv : Wo;
        unsigned short* dst = sel == 0 ? wqT : sel == 1 ? wkT : sel == 2 ? wvT : woT;
        dst[(size_t)l * 65536 + n * 256 + kk] = f2bf(src[j]);
    } else if (blk < 8192) {
        int i = (blk - 4096) * 256 + tid;
        int l = i >> 18, rem = i & 262143, kk = rem >> 10, n = rem & 1023;
        w1T[(size_t)l * 262144 + (size_t)n * 256 + kk] = f2bf(W1[i]);
    } else if (blk < 9216) {
        int j = (blk - 8192) * 256 + tid;
        int l = j >> 16, rem = j & 65535, kk = rem >> 7, n = rem & 127;
        w2T[(size_t)l * 65536 + (size_t)n * 512 + kk] = f2bf(W2[j]);
    } else {
        int w = (blk - 9216) * 256 + tid;   // 0..8191
        int r = w >> 4, wi = w & 15;
        const int* src = mask + r * NSEQ + wi * 32;
        unsigned acc = 0;
#pragma unroll
        for (int j = 0; j < 32; j++) acc |= (src[j] != 0 ? 1u : 0u) << j;
        bits[w] = acc;
    }
}

// ---------------------------------------------------------------------------
// x = input + pos (fp32 + bf16) ; xv = input_v + pos (bf16 only)
// ---------------------------------------------------------------------------
__global__ void add_pos_kernel(const float* __restrict__ in,
                               const float* __restrict__ inv,
                               const float* __restrict__ pos,
                               float* __restrict__ x,
                               unsigned short* __restrict__ xb,
                               unsigned short* __restrict__ xvb,
                               int total) {
    int i = blockIdx.x * blockDim.x + threadIdx.x;
    if (i < total) {
        float pe = pos[i % ND];
        float a = in[i] + pe;
        float b = inv[i] + pe;
        x[i] = a;
        xb[i] = f2bf(a);
        xvb[i] = f2bf(b);
    }
}

// ---------------------------------------------------------------------------
// Fused QKV GEMM: grid (6, 64). blockIdx.x: 0,1->Q  2,3->K  4,5->V.
// Q output pre-scaled by 1/sqrt(dk) so attention skips the per-score scale.
// Output bf16 head-blocked: [(row/512)*8 + col/32][row%512][col%32]
// ---------------------------------------------------------------------------
__global__ __launch_bounds__(256) void qkv_mfma_kernel(
        const unsigned short* __restrict__ xb,
        const unsigned short* __restrict__ xvb,
        const unsigned short* __restrict__ WqT, const unsigned short* __restrict__ WkT,
        const unsigned short* __restrict__ WvT,
        const float* __restrict__ bq, const float* __restrict__ bk,
        const float* __restrict__ bv,
        unsigned short* __restrict__ qo, unsigned short* __restrict__ ko,
        unsigned short* __restrict__ vo) {
    int proj = blockIdx.x >> 1;
    const unsigned short* A  = (proj == 2) ? xvb : xb;
    const unsigned short* Bt = (proj == 0) ? WqT : (proj == 1) ? WkT : WvT;
    const float* bias        = (proj == 0) ? bq  : (proj == 1) ? bk  : bv;
    unsigned short* Cb       = (proj == 0) ? qo  : (proj == 1) ? ko  : vo;
    float qscale = (proj == 0) ? 0.17677669529663687f : 1.f;

    __shared__ unsigned short As[128 * 32];
    __shared__ unsigned short Bs[128 * 32];
    int tid = threadIdx.x;
    int wave = tid >> 6, lane = tid & 63;
    int rowBase = blockIdx.y * 128, colBase = (blockIdx.x & 1) * 128;
    int m0w = (wave & 1) * 64, n0w = (wave >> 1) * 64;
    int lr = lane & 15, quad = lane >> 4;

    floatx4 acc[4][4];
#pragma unroll
    for (int mi = 0; mi < 4; mi++)
#pragma unroll
        for (int nj = 0; nj < 4; nj++) acc[mi][nj] = (floatx4)0.0f;

    for (int kt = 0; kt < DMODEL; kt += 32) {
#pragma unroll
        for (int t = 0; t < 2; t++) {
            int idx = t * 256 + tid;
            int row = idx >> 2, kv8 = (idx & 3) * 8;
            async_ld16(A + (size_t)(rowBase + row) * DMODEL + kt + kv8, &As[idx * 8]);
            async_ld16(Bt + (size_t)(colBase + row) * DMODEL + kt + kv8, &Bs[idx * 8]);
        }
        __syncthreads();
        bf16x8 af[4], bfr[4];
#pragma unroll
        for (int mi = 0; mi < 4; mi++)
            af[mi] = *(const bf16x8*)&As[(m0w + mi * 16 + lr) * 32 + quad * 8];
#pragma unroll
        for (int nj = 0; nj < 4; nj++)
            bfr[nj] = *(const bf16x8*)&Bs[(n0w + nj * 16 + lr) * 32 + quad * 8];
#pragma unroll
        for (int mi = 0; mi < 4; mi++)
#pragma unroll
            for (int nj = 0; nj < 4; nj++)
                acc[mi][nj] = __builtin_amdgcn_mfma_f32_16x16x32_bf16(
                    af[mi], bfr[nj], acc[mi][nj], 0, 0, 0);
        __syncthreads();
    }

#pragma unroll
    for (int mi = 0; mi < 4; mi++) {
#pragma unroll
        for (int r = 0; r < 4; r++) {
            int grow = rowBase + m0w + mi * 16 + quad * 4 + r;
#pragma unroll
            for (int nj = 0; nj < 4; nj++) {
                int gcol = colBase + n0w + nj * 16 + lr;
                float c = (acc[mi][nj][r] + bias[gcol]) * qscale;
                size_t off = ((size_t)((grow >> 9) * 8 + (gcol >> 5)) << 14)
                           + (size_t)(grow & 511) * 32 + (gcol & 31);
                Cb[off] = f2bf(c);
            }
        }
    }
}

// ---------------------------------------------------------------------------
// Generic MFMA GEMM (FFN1): C = A @ Bt^T + bias, optional GELU, bf16 out.
// ---------------------------------------------------------------------------
__global__ __launch_bounds__(256) void gemm_mfma_kernel(
        const unsigned short* __restrict__ A,
        const unsigned short* __restrict__ Bt,
        const float* __restrict__ bias,
        unsigned short* __restrict__ Cb,
        int M, int K, int N, int act) {
    __shared__ unsigned short As[128 * 32];
    __shared__ unsigned short Bs[128 * 32];
    int tid = threadIdx.x;
    int wave = tid >> 6, lane = tid & 63;
    int rowBase = blockIdx.y * 128, colBase = blockIdx.x * 128;
    int m0w = (wave & 1) * 64, n0w = (wave >> 1) * 64;
    int lr = lane & 15, quad = lane >> 4;

    floatx4 acc[4][4];
#pragma unroll
    for (int mi = 0; mi < 4; mi++)
#pragma unroll
        for (int nj = 0; nj < 4; nj++) acc[mi][nj] = (floatx4)0.0f;

    for (int kt = 0; kt < K; kt += 32) {
#pragma unroll
        for (int t = 0; t < 2; t++) {
            int idx = t * 256 + tid;
            int row = idx >> 2, kv8 = (idx & 3) * 8;
            async_ld16(A + (size_t)(rowBase + row) * K + kt + kv8, &As[idx * 8]);
            async_ld16(Bt + (size_t)(colBase + row) * K + kt + kv8, &Bs[idx * 8]);
        }
        __syncthreads();
        bf16x8 af[4], bfr[4];
#pragma unroll
        for (int mi = 0; mi < 4; mi++)
            af[mi] = *(const bf16x8*)&As[(m0w + mi * 16 + lr) * 32 + quad * 8];
#pragma unroll
        for (int nj = 0; nj < 4; nj++)
            bfr[nj] = *(const bf16x8*)&Bs[(n0w + nj * 16 + lr) * 32 + quad * 8];
#pragma unroll
        for (int mi = 0; mi < 4; mi++)
#pragma unroll
            for (int nj = 0; nj < 4; nj++)
                acc[mi][nj] = __builtin_amdgcn_mfma_f32_16x16x32_bf16(
                    af[mi], bfr[nj], acc[mi][nj], 0, 0, 0);
        __syncthreads();
    }

#pragma unroll
    for (int mi = 0; mi < 4; mi++) {
#pragma unroll
        for (int r = 0; r < 4; r++) {
            int grow = rowBase + m0w + mi * 16 + quad * 4 + r;
#pragma unroll
            for (int nj = 0; nj < 4; nj++) {
                int gcol = colBase + n0w + nj * 16 + lr;
                float c = acc[mi][nj][r] + bias[gcol];
                if (act) c = gelu_f(c);
                Cb[(size_t)grow * N + gcol] = f2bf(c);
            }
        }
    }
}

// ---------------------------------------------------------------------------
// Fused Wo-GEMM + bias + residual + LayerNorm.
// 16 rows x 256 cols per block, ONE wave (64 thr), grid 512 -> 2 blocks/CU
// so staging latency of independent blocks overlaps (was 1 block/CU).
// ---------------------------------------------------------------------------
__global__ __launch_bounds__(64) void wo_ln_kernel(
        const unsigned short* __restrict__ A,     // ab_b [8192][256]
        const unsigned short* __restrict__ Bt,    // woT [256][256]
        const float* __restrict__ bias,
        const float* __restrict__ g, const float* __restrict__ be,
        float* __restrict__ xf, unsigned short* __restrict__ xb) {
    __shared__ unsigned short As[16 * 32];
    __shared__ unsigned short Bs[256 * 32];
    int tid = threadIdx.x;
    int l16 = tid & 15, quad = tid >> 4;
    int rowBase = blockIdx.x * 16;

    floatx4 acc[16];
#pragma unroll
    for (int t = 0; t < 16; t++) acc[t] = (floatx4)0.0f;

    for (int kt = 0; kt < 256; kt += 32) {
        {
            int row = tid >> 2, kv8 = (tid & 3) * 8;
            async_ld16(A + (size_t)(rowBase + row) * 256 + kt + kv8, &As[tid * 8]);
        }
#pragma unroll
        for (int t = 0; t < 16; t++) {
            int idx = t * 64 + tid;
            int row = idx >> 2, kv8 = (idx & 3) * 8;
            async_ld16(Bt + (size_t)row * 256 + kt + kv8, &Bs[idx * 8]);
        }
        __syncthreads();
        bf16x8 af = *(const bf16x8*)&As[l16 * 32 + quad * 8];
#pragma unroll
        for (int t = 0; t < 16; t++) {
            bf16x8 bfr = *(const bf16x8*)&Bs[(t * 16 + l16) * 32 + quad * 8];
            acc[t] = __builtin_amdgcn_mfma_f32_16x16x32_bf16(af, bfr, acc[t], 0, 0, 0);
        }
        __syncthreads();
    }

    float bcol[16], gc[16], bec[16];
#pragma unroll
    for (int t = 0; t < 16; t++) {
        int c = t * 16 + l16;
        bcol[t] = bias[c]; gc[t] = g[c]; bec[t] = be[c];
    }
#pragma unroll
    for (int r = 0; r < 4; r++) {
        int grow = rowBase + quad * 4 + r;
        float v[16], s = 0.f, s2 = 0.f;
#pragma unroll
        for (int t = 0; t < 16; t++) {
            int c = t * 16 + l16;
            float val = acc[t][r] + bcol[t] + xf[(size_t)grow * 256 + c];
            v[t] = val; s += val; s2 += val * val;
        }
#pragma unroll
        for (int off = 1; off <= 8; off <<= 1) {
            s += __shfl_xor(s, off);
            s2 += __shfl_xor(s2, off);
        }
        float mean = s * (1.f / 256.f);
        float var = s2 * (1.f / 256.f) - mean * mean;
        float rstd = rsqrtf(var + 1e-5f);
#pragma unroll
        for (int t = 0; t < 16; t++) {
            int c = t * 16 + l16;
            float o = (v[t] - mean) * rstd * gc[t] + bec[t];
            xf[(size_t)grow * 256 + c] = o;
            xb[(size_t)grow * 256 + c] = f2bf(o);
        }
    }
}

// ---------------------------------------------------------------------------
// Fused FFN2(grouped) + bias + residual + LayerNorm. 64 rows x 128 cols.
// ---------------------------------------------------------------------------
__global__ __launch_bounds__(128) void ffn2_ln_kernel(
        const unsigned short* __restrict__ A,     // h_b [16384][512]
        const unsigned short* __restrict__ Bt,    // w2T [128][512]
        const float* __restrict__ bias,           // [128]
        const float* __restrict__ g, const float* __restrict__ be,
        float* __restrict__ xf, unsigned short* __restrict__ xb) {
    __shared__ unsigned short As[64 * 32];
    __shared__ unsigned short Bs[128 * 32];
    __shared__ float redS[64][2], redQ[64][2];
    int tid = threadIdx.x;
    int wave = tid >> 6, lane = tid & 63, l16 = lane & 15, quad = lane >> 4;
    int rowBase = blockIdx.x * 64;
    int n0w = wave * 64;

    floatx4 acc[4][4];
#pragma unroll
    for (int mi = 0; mi < 4; mi++)
#pragma unroll
        for (int nj = 0; nj < 4; nj++) acc[mi][nj] = (floatx4)0.0f;

    for (int kt = 0; kt < 512; kt += 32) {
#pragma unroll
        for (int t = 0; t < 2; t++) {
            int idx = t * 128 + tid;
            int row = idx >> 2, kv8 = (idx & 3) * 8;
            async_ld16(A + (size_t)(rowBase + row) * 512 + kt + kv8, &As[idx * 8]);
        }
#pragma unroll
        for (int t = 0; t < 4; t++) {
            int idx = t * 128 + tid;
            int row = idx >> 2, kv8 = (idx & 3) * 8;
            async_ld16(Bt + (size_t)row * 512 + kt + kv8, &Bs[idx * 8]);
        }
        __syncthreads();
        bf16x8 af[4], bfr[4];
#pragma unroll
        for (int mi = 0; mi < 4; mi++)
            af[mi] = *(const bf16x8*)&As[(mi * 16 + l16) * 32 + quad * 8];
#pragma unroll
        for (int nj = 0; nj < 4; nj++)
            bfr[nj] = *(const bf16x8*)&Bs[(n0w + nj * 16 + l16) * 32 + quad * 8];
#pragma unroll
        for (int mi = 0; mi < 4; mi++)
#pragma unroll
            for (int nj = 0; nj < 4; nj++)
                acc[mi][nj] = __builtin_amdgcn_mfma_f32_16x16x32_bf16(
                    af[mi], bfr[nj], acc[mi][nj], 0, 0, 0);
        __syncthreads();
    }

#pragma unroll
    for (int mi = 0; mi < 4; mi++) {
#pragma unroll
        for (int r = 0; r < 4; r++) {
            int row = mi * 16 + quad * 4 + r;       // 0..63
            int grow = rowBase + row;
            int token = grow >> 1, dbase = (grow & 1) * 128;
            float s = 0.f, s2 = 0.f;
#pragma unroll
            for (int nj = 0; nj < 4; nj++) {
                int gcol = n0w + nj * 16 + l16;
                float val = acc[mi][nj][r] + bias[gcol]
                          + xf[(size_t)token * 256 + dbase + gcol];
                acc[mi][nj][r] = val;
                s += val; s2 += val * val;
            }
#pragma unroll
            for (int off = 1; off <= 8; off <<= 1) {
                s += __shfl_xor(s, off);
                s2 += __shfl_xor(s2, off);
            }
            if (l16 == 0) { redS[row][wave] = s; redQ[row][wave] = s2; }
        }
    }
    __syncthreads();

#pragma unroll
    for (int mi = 0; mi < 4; mi++) {
#pragma unroll
        for (int r = 0; r < 4; r++) {
            int row = mi * 16 + quad * 4 + r;
            int grow = rowBase + row;
            int token = grow >> 1, dbase = (grow & 1) * 128;
            float ts = redS[row][0] + redS[row][1] + redS[row ^ 1][0] + redS[row ^ 1][1];
            float tq = redQ[row][0] + redQ[row][1] + redQ[row ^ 1][0] + redQ[row ^ 1][1];
            float mean = ts * (1.f / 256.f);
            float var = tq * (1.f / 256.f) - mean * mean;
            float rstd = rsqrtf(var + 1e-5f);
#pragma unroll
            for (int nj = 0; nj < 4; nj++) {
                int gcol = n0w + nj * 16 + l16;
                int d = dbase + gcol;
                float o = (acc[mi][nj][r] - mean) * rstd * g[d] + be[d];
                xf[(size_t)token * 256 + d] = o;
                xb[(size_t)token * 256 + d] = f2bf(o);
            }
        }
    }
}

// ---------------------------------------------------------------------------
// MFMA attention. Grid = 1024 blocks.
// bid decode (XCD swizzle): qg = bid>>7, bh = bid&127 -> all 8 q-group blocks
// of one (b,h) have bid==h (mod 8) -> same XCD -> K/V L2-resident (1MB/XCD).
// K fragments are read DIRECTLY from global (coalesced 1KB/wave per frag,
// L2-hot) -- no K LDS, no 8-way-conflicted ds_reads. LDS = V only (32KB)
// -> 4 blocks/CU via __launch_bounds__(256,4).
// V staged via global_load_lds into two d-block halves Vs[db][k*16+d],
// consumed with ds_read_b64_tr_b16 (HW 4x16 transpose), software-pipelined
// one iteration ahead so DS latency hides under QK^T+softmax.
// Q arrives pre-scaled by 1/sqrt(dk) from qkv_mfma_kernel.
// ---------------------------------------------------------------------------
__global__ __launch_bounds__(256, 4) void attn_mfma_kernel(
        const unsigned short* __restrict__ q, const unsigned short* __restrict__ k,
        const unsigned short* __restrict__ v, unsigned short* __restrict__ o,
        const unsigned* __restrict__ mbits_g, int use_mask) {
    int bid = blockIdx.x;
    int qg = bid >> 7;          // 0..7
    int bh = bid & 127;         // XCD = bh & 7 = h
    int h = bh & 7, b = bh >> 3;
    int tid = threadIdx.x;

    __shared__ unsigned short Vs[2][NSEQ * 16];     // 32KB  [db][k*16+d]

    const unsigned short* kbase = k + (size_t)(b * 8 + h) * (NSEQ * DK);
    const unsigned short* vbase = v + (size_t)(b * 8 + h) * (NSEQ * DK);

    // V split: chunk c (16B) of Vs[db] covers k=c>>1, d = db*16 + (c&1)*8 .. +7
#pragma unroll
    for (int db = 0; db < 2; db++) {
#pragma unroll
        for (int t = 0; t < 4; t++) {
            int c = t * 256 + tid;                  // 0..1023
            int kk = c >> 1, half = c & 1;
            async_ld16(vbase + (size_t)kk * 32 + db * 16 + half * 8,
                       &Vs[db][c * 8]);
        }
    }

    int wave = tid >> 6, lane = tid & 63, l16 = lane & 15, quad = lane >> 4;
    int qbase = qg * 64 + wave * 16;

    bf16x8 qf = *(const bf16x8*)(q + ((size_t)(b * 8 + h) * NSEQ + qbase + l16) * 32 + quad * 8);

    unsigned mw[16];
    if (use_mask) {
        const uint4* mr = (const uint4*)(mbits_g + (size_t)(qbase + l16) * 16);
#pragma unroll
        for (int w = 0; w < 4; w++) *(uint4*)&mw[w * 4] = mr[w];
    } else {
#pragma unroll
        for (int w = 0; w < 16; w++) mw[w] = 0;
    }
    __syncthreads();

    unsigned va0 = (unsigned)(size_t)&Vs[0][0] + (unsigned)(lane * 8);
    unsigned va1 = (unsigned)(size_t)&Vs[1][0] + (unsigned)(lane * 8);

    // K fragment base: row r -> 16B at kfrag + r*32 elems
    const unsigned short* kfrag = kbase + (size_t)l16 * DK + quad * 8;

    floatx4 oT0 = (floatx4)0.f, oT1 = (floatx4)0.f;
    float m_run = -INFINITY, l_part = 0.f;

    uint32x2 t00, t01, t10, t11;
#define TR_ISSUE(cc)                                                      \
    asm volatile("ds_read_b64_tr_b16 %0, %4\n\t"                          \
                 "ds_read_b64_tr_b16 %1, %4 offset:512\n\t"               \
                 "ds_read_b64_tr_b16 %2, %5\n\t"                          \
                 "ds_read_b64_tr_b16 %3, %5 offset:512"                   \
                 : "=&v"(t00), "=&v"(t01), "=&v"(t10), "=&v"(t11)         \
                 : "v"(va0 + (unsigned)((cc) * 1024)),                    \
                   "v"(va1 + (unsigned)((cc) * 1024)))
    TR_ISSUE(0);

#pragma unroll
    for (int c = 0; c < 16; c++) {
        int kkb = c * 32;
        bf16x8 k0 = *(const bf16x8*)(kfrag + (size_t)kkb * DK);
        bf16x8 k1 = *(const bf16x8*)(kfrag + (size_t)(kkb + 16) * DK);
        floatx4 s0 = __builtin_amdgcn_mfma_f32_16x16x32_bf16(k0, qf, (floatx4)0.f, 0, 0, 0);
        floatx4 s1 = __builtin_amdgcn_mfma_f32_16x16x32_bf16(k1, qf, (floatx4)0.f, 0, 0, 0);

        float sv[8];
#pragma unroll
        for (int r = 0; r < 4; r++) { sv[r] = s0[r]; sv[4 + r] = s1[r]; }
        if (use_mask) {
            unsigned wb = mw[c];
#pragma unroll
            for (int r = 0; r < 4; r++) {
                if ((wb >> (quad * 4 + r)) & 1) sv[r] = -INFINITY;
                if ((wb >> (16 + quad * 4 + r)) & 1) sv[4 + r] = -INFINITY;
            }
        }
        float mx = fmaxf(fmaxf(fmaxf(sv[0], sv[1]), fmaxf(sv[2], sv[3])),
                         fmaxf(fmaxf(sv[4], sv[5]), fmaxf(sv[6], sv[7])));
        mx = fmaxf(mx, __shfl_xor(mx, 16));
        mx = fmaxf(mx, __shfl_xor(mx, 32));
        // wave-uniform exact skip: if no lane's block-max exceeds the running
        // max, mnew == m_run for every lane and the rescale is a no-op.
        if (!__all(mx <= m_run)) {
            float mnew = fmaxf(m_run, mx);
            float corr = (m_run == mnew) ? 1.f : __expf(m_run - mnew);
            l_part *= corr;
            oT0 *= corr; oT1 *= corr;
            m_run = mnew;
        }
        float p[8];
#pragma unroll
        for (int j = 0; j < 8; j++) {
            float e = __expf(sv[j] - m_run);
            p[j] = (sv[j] > -INFINITY) ? e : 0.f;
            l_part += p[j];
        }
        union { bf16x8 v8; unsigned u[4]; } pf;
#pragma unroll
        for (int j = 0; j < 4; j++)
            asm("v_cvt_pk_bf16_f32 %0, %1, %2"
                : "=v"(pf.u[j]) : "v"(p[2 * j]), "v"(p[2 * j + 1]));

        // consume tr(c); issue tr(c+1) after the PV MFMAs so its DS latency
        // hides under the next iteration's QK^T + softmax.
        asm volatile("s_waitcnt lgkmcnt(0)");
        __builtin_amdgcn_sched_barrier(0);
        union { bf16x8 v8; uint32x2 u[2]; } av0, av1;
        av0.u[0] = t00; av0.u[1] = t01;
        av1.u[0] = t10; av1.u[1] = t11;

        oT0 = __builtin_amdgcn_mfma_f32_16x16x32_bf16(av0.v8, pf.v8, oT0, 0, 0, 0);
        oT1 = __builtin_amdgcn_mfma_f32_16x16x32_bf16(av1.v8, pf.v8, oT1, 0, 0, 0);
        if (c < 15) TR_ISSUE(c + 1);
    }
#undef TR_ISSUE

    float l = l_part;
    l += __shfl_xor(l, 16);
    l += __shfl_xor(l, 32);
    float invl = (l > 0.f) ? 1.f / l : 0.f;

    unsigned short* orow = o + ((size_t)(b * NSEQ + qbase + l16)) * DMODEL + h * DK;
#pragma unroll
    for (int r = 0; r < 4; r++) {
        orow[quad * 4 + r]      = f2bf(oT0[r] * invl);
        orow[16 + quad * 4 + r] = f2bf(oT1[r] * invl);
    }
}

// Final LN: out = LayerNorm(x) * gf + bf (fp32)
__global__ __launch_bounds__(256) void final_ln_kernel(
        const float* __restrict__ a,
        const float* __restrict__ g, const float* __restrict__ be,
        float* __restrict__ out) {
    int t = blockIdx.x;
    int d = threadIdx.x;
    size_t idx = (size_t)t * DMODEL + d;
    float v = a[idx];
    float s = v, s2 = v * v;
#pragma unroll
    for (int off = 32; off; off >>= 1) {
        s  += __shfl_xor(s, off);
        s2 += __shfl_xor(s2, off);
    }
    __shared__ float ws1[4], ws2[4];
    int wid = d >> 6;
    if ((d & 63) == 0) { ws1[wid] = s; ws2[wid] = s2; }
    __syncthreads();
    s  = ws1[0] + ws1[1] + ws1[2] + ws1[3];
    s2 = ws2[0] + ws2[1] + ws2[2] + ws2[3];
    float mean = s * (1.f / DMODEL);
    float var = s2 * (1.f / DMODEL) - mean * mean;
    float rstd = rsqrtf(var + 1e-5f);
    out[idx] = (v - mean) * rstd * g[d] + be[d];
}

// ---------------------------------------------------------------------------
extern "C" void kernel_launch(void* const* d_in, const int* in_sizes, int n_in,
                              void* d_out, int out_size, void* d_ws, size_t ws_size,
                              hipStream_t stream) {
    const float* input  = (const float*)d_in[0];
    const float* inputv = (const float*)d_in[1];
    const float* pos    = (const float*)d_in[2];
    const float* Wq = (const float*)d_in[3];
    const float* bq = (const float*)d_in[4];
    const float* Wk = (const float*)d_in[5];
    const float* bk = (const float*)d_in[6];
    const float* Wv = (const float*)d_in[7];
    const float* bv = (const float*)d_in[8];
    const float* Wo = (const float*)d_in[9];
    const float* bo = (const float*)d_in[10];
    const float* W1 = (const float*)d_in[11];
    const float* b1 = (const float*)d_in[12];
    const float* W2 = (const float*)d_in[13];
    const float* b2 = (const float*)d_in[14];
    const float* g1 = (const float*)d_in[15];
    const float* be1 = (const float*)d_in[16];
    const float* g2 = (const float*)d_in[17];
    const float* be2 = (const float*)d_in[18];
    const float* gf = (const float*)d_in[19];
    const float* bff = (const float*)d_in[20];
    const int* mask = (const int*)d_in[21];

    float* out = (float*)d_out;

    // Workspace layout (bytes), ~37 MB
    char* wsb = (char*)d_ws;
    float* x_f  = (float*)(wsb + ((size_t)0 << 20));                    // 8 MB
    unsigned short* x_b  = (unsigned short*)(wsb + ((size_t)8 << 20));  // 4 MB
    unsigned short* xv_b = (unsigned short*)(wsb + ((size_t)12 << 20)); // 4 MB
    unsigned short* qb_b = (unsigned short*)(wsb + ((size_t)16 << 20)); // 4 MB
    unsigned short* kb_b = (unsigned short*)(wsb + ((size_t)20 << 20)); // 4 MB
    unsigned short* vb_b = (unsigned short*)(wsb + ((size_t)24 << 20)); // 4 MB
    unsigned short* ab_b = (unsigned short*)(wsb + ((size_t)28 << 20)); // 4 MB
    unsigned short* h_b  = qb_b;  // 16 MB alias over qb..ab (dead during FFN)
    unsigned short* wqT = (unsigned short*)(wsb + ((size_t)32 << 20));
    unsigned short* wkT = wqT + (size_t)4 * 65536;
    unsigned short* wvT = wkT + (size_t)4 * 65536;
    unsigned short* woT = wvT + (size_t)4 * 65536;
    unsigned short* w1T = woT + (size_t)4 * 65536;   // 4 x 262144
    unsigned short* w2T = w1T + (size_t)4 * 262144;  // 4 x 65536
    unsigned* mbits = (unsigned*)(wsb + ((size_t)37 << 20));            // 32 KB

    const size_t TOK = (size_t)BN * DMODEL;

    // --- preconversions (2 dispatches) ---
    conv_all_kernel<<<9248, 256, 0, stream>>>(Wq, Wk, Wv, Wo, W1, W2, mask,
                                              wqT, wkT, wvT, woT, w1T, w2T, mbits);
    add_pos_kernel<<<(int)((TOK + 255) / 256), 256, 0, stream>>>(
        input, inputv, pos, x_f, x_b, xv_b, (int)TOK);

    for (int i = 0; i < NLAYER; i++) {
        const unsigned short* WqT_i = wqT + (size_t)i * 65536;
        const unsigned short* WkT_i = wkT + (size_t)i * 65536;
        const unsigned short* WvT_i = wvT + (size_t)i * 65536;
        const unsigned short* WoT_i = woT + (size_t)i * 65536;
        const unsigned short* W1T_i = w1T + (size_t)i * 262144;
        const unsigned short* W2T_i = w2T + (size_t)i * 65536;

        qkv_mfma_kernel<<<dim3(6, 64), 256, 0, stream>>>(
            x_b, xv_b, WqT_i, WkT_i, WvT_i,
            bq + i * DMODEL, bk + i * DMODEL, bv + i * DMODEL,
            qb_b, kb_b, vb_b);

        attn_mfma_kernel<<<BDIM * NHEAD * 8, 256, 0, stream>>>(
            qb_b, kb_b, vb_b, ab_b, mbits, (i & 1));

        wo_ln_kernel<<<BN / 16, 64, 0, stream>>>(
            ab_b, WoT_i, bo + i * DMODEL,
            g1 + i * DMODEL, be1 + i * DMODEL, x_f, x_b);

        gemm_mfma_kernel<<<dim3(8, 64), 256, 0, stream>>>(
            x_b, W1T_i, b1 + i * DFF, h_b, BN, DMODEL, DFF, 1);

        ffn2_ln_kernel<<<(2 * BN) / 64, 128, 0, stream>>>(
            h_b, W2T_i, b2 + i * (DMODEL / 2),
            g2 + i * DMODEL, be2 + i * DMODEL, x_f, x_b);
    }

    final_ln_kernel<<<BN, DMODEL, 0, stream>>>(x_f, gf, bff, out);
}

// Round 4
// 454.556 us; speedup vs baseline: 1.1028x; 1.0160x over previous
//
#include <hip/hip_runtime.h>
#include <hip/hip_bf16.h>
#include <math.h>

// Problem constants (LightGFormer): B=16, N=512, D=256, L=4, H=8, dk=32, Dff=1024
#define BDIM 16
#define NSEQ 512
#define DMODEL 256
#define NLAYER 4
#define NHEAD 8
#define DK 32
#define DFF 1024
#define BN (BDIM * NSEQ)          // 8192 tokens
#define ND (NSEQ * DMODEL)        // 131072

typedef __bf16 bf16x8 __attribute__((ext_vector_type(8)));
typedef float floatx4 __attribute__((ext_vector_type(4)));
typedef unsigned uint32x2 __attribute__((ext_vector_type(2)));

// RNE float->bf16 bits
static __device__ __forceinline__ unsigned short f2bf(float f) {
    unsigned u = __float_as_uint(f);
    unsigned r = (u + 0x7FFFu + ((u >> 16) & 1u)) >> 16;
    return (unsigned short)r;
}

// async 16-byte global->LDS copy (wave-uniform LDS base + lane*16 required)
static __device__ __forceinline__ void async_ld16(const unsigned short* g,
                                                  unsigned short* l) {
    __builtin_amdgcn_global_load_lds(
        (const __attribute__((address_space(1))) unsigned int*)g,
        (__attribute__((address_space(3))) unsigned int*)l, 16, 0, 0);
}

// sigmoid-form tanh-approx GELU, |err| < 1e-3 vs exact
static __device__ __forceinline__ float gelu_f(float c) {
    float u = 0.7978845608028654f * (c + 0.044715f * c * c * c);
    return c * (1.f / (1.f + __expf(-2.f * u)));
}

// ---------------------------------------------------------------------------
// All weight conversions + mask pack in ONE dispatch.
// ---------------------------------------------------------------------------
__global__ void conv_all_kernel(const float* __restrict__ Wq, const float* __restrict__ Wk,
                                const float* __restrict__ Wv, const float* __restrict__ Wo,
                                const float* __restrict__ W1, const float* __restrict__ W2,
                                const int* __restrict__ mask,
                                unsigned short* __restrict__ wqT, unsigned short* __restrict__ wkT,
                                unsigned short* __restrict__ wvT, unsigned short* __restrict__ woT,
                                unsigned short* __restrict__ w1T, unsigned short* __restrict__ w2T,
                                unsigned* __restrict__ bits) {
    int blk = blockIdx.x, tid = threadIdx.x;
    if (blk < 4096) {
        int i = blk * 256 + tid;
        int sel = i >> 18;
        int j = i & 262143;
        int l = j >> 16, rem = j & 65535, kk = rem >> 8, n = rem & 255;
        const float* src = sel == 0 ? Wq : sel == 1 ? Wk : sel == 2 ? Wv : Wo;
        unsigned short* dst = sel == 0 ? wqT : sel == 1 ? wkT : sel == 2 ? wvT : woT;
        dst[(size_t)l * 65536 + n * 256 + kk] = f2bf(src[j]);
    } else if (blk < 8192) {
        int i = (blk - 4096) * 256 + tid;
        int l = i >> 18, rem = i & 262143, kk = rem >> 10, n = rem & 1023;
        w1T[(size_t)l * 262144 + (size_t)n * 256 + kk] = f2bf(W1[i]);
    } else if (blk < 9216) {
        int j = (blk - 8192) * 256 + tid;
        int l = j >> 16, rem = j & 65535, kk = rem >> 7, n = rem & 127;
        w2T[(size_t)l * 65536 + (size_t)n * 512 + kk] = f2bf(W2[j]);
    } else {
        int w = (blk - 9216) * 256 + tid;   // 0..8191
        int r = w >> 4, wi = w & 15;
        const int* src = mask + r * NSEQ + wi * 32;
        unsigned acc = 0;
#pragma unroll
        for (int j = 0; j < 32; j++) acc |= (src[j] != 0 ? 1u : 0u) << j;
        bits[w] = acc;
    }
}

// ---------------------------------------------------------------------------
// x = input + pos (fp32 + bf16) ; xv = input_v + pos (bf16 only)
// ---------------------------------------------------------------------------
__global__ void add_pos_kernel(const float* __restrict__ in,
                               const float* __restrict__ inv,
                               const float* __restrict__ pos,
                               float* __restrict__ x,
                               unsigned short* __restrict__ xb,
                               unsigned short* __restrict__ xvb,
                               int total) {
    int i = blockIdx.x * blockDim.x + threadIdx.x;
    if (i < total) {
        float pe = pos[i % ND];
        float a = in[i] + pe;
        float b = inv[i] + pe;
        x[i] = a;
        xb[i] = f2bf(a);
        xvb[i] = f2bf(b);
    }
}

// ---------------------------------------------------------------------------
// Fused QKV GEMM: grid (6, 64). blockIdx.x: 0,1->Q  2,3->K  4,5->V.
// Q output pre-scaled by 1/sqrt(dk).
// LDS XOR swizzle (both-sides, rule #21): staging source chunk c^(row&3)
// (stays in the same 64B segment -> coalescing kept); fragment read uses
// quad^(lr&3). Bank aliasing 8-way -> 4-way.
// ---------------------------------------------------------------------------
__global__ __launch_bounds__(256) void qkv_mfma_kernel(
        const unsigned short* __restrict__ xb,
        const unsigned short* __restrict__ xvb,
        const unsigned short* __restrict__ WqT, const unsigned short* __restrict__ WkT,
        const unsigned short* __restrict__ WvT,
        const float* __restrict__ bq, const float* __restrict__ bk,
        const float* __restrict__ bv,
        unsigned short* __restrict__ qo, unsigned short* __restrict__ ko,
        unsigned short* __restrict__ vo) {
    int proj = blockIdx.x >> 1;
    const unsigned short* A  = (proj == 2) ? xvb : xb;
    const unsigned short* Bt = (proj == 0) ? WqT : (proj == 1) ? WkT : WvT;
    const float* bias        = (proj == 0) ? bq  : (proj == 1) ? bk  : bv;
    unsigned short* Cb       = (proj == 0) ? qo  : (proj == 1) ? ko  : vo;
    float qscale = (proj == 0) ? 0.17677669529663687f : 1.f;

    __shared__ unsigned short As[128 * 32];
    __shared__ unsigned short Bs[128 * 32];
    int tid = threadIdx.x;
    int wave = tid >> 6, lane = tid & 63;
    int rowBase = blockIdx.y * 128, colBase = (blockIdx.x & 1) * 128;
    int m0w = (wave & 1) * 64, n0w = (wave >> 1) * 64;
    int lr = lane & 15, quad = lane >> 4;
    int qx = quad ^ (lr & 3);          // swizzled chunk for fragment reads

    floatx4 acc[4][4];
#pragma unroll
    for (int mi = 0; mi < 4; mi++)
#pragma unroll
        for (int nj = 0; nj < 4; nj++) acc[mi][nj] = (floatx4)0.0f;

    for (int kt = 0; kt < DMODEL; kt += 32) {
#pragma unroll
        for (int t = 0; t < 2; t++) {
            int idx = t * 256 + tid;
            int row = idx >> 2, kv8 = ((idx ^ row) & 3) * 8;   // c ^ (row&3)
            async_ld16(A + (size_t)(rowBase + row) * DMODEL + kt + kv8, &As[idx * 8]);
            async_ld16(Bt + (size_t)(colBase + row) * DMODEL + kt + kv8, &Bs[idx * 8]);
        }
        __syncthreads();
        bf16x8 af[4], bfr[4];
#pragma unroll
        for (int mi = 0; mi < 4; mi++)
            af[mi] = *(const bf16x8*)&As[(m0w + mi * 16 + lr) * 32 + qx * 8];
#pragma unroll
        for (int nj = 0; nj < 4; nj++)
            bfr[nj] = *(const bf16x8*)&Bs[(n0w + nj * 16 + lr) * 32 + qx * 8];
#pragma unroll
        for (int mi = 0; mi < 4; mi++)
#pragma unroll
            for (int nj = 0; nj < 4; nj++)
                acc[mi][nj] = __builtin_amdgcn_mfma_f32_16x16x32_bf16(
                    af[mi], bfr[nj], acc[mi][nj], 0, 0, 0);
        __syncthreads();
    }

#pragma unroll
    for (int mi = 0; mi < 4; mi++) {
#pragma unroll
        for (int r = 0; r < 4; r++) {
            int grow = rowBase + m0w + mi * 16 + quad * 4 + r;
#pragma unroll
            for (int nj = 0; nj < 4; nj++) {
                int gcol = colBase + n0w + nj * 16 + lr;
                float c = (acc[mi][nj][r] + bias[gcol]) * qscale;
                size_t off = ((size_t)((grow >> 9) * 8 + (gcol >> 5)) << 14)
                           + (size_t)(grow & 511) * 32 + (gcol & 31);
                Cb[off] = f2bf(c);
            }
        }
    }
}

// ---------------------------------------------------------------------------
// Generic MFMA GEMM (FFN1): C = A @ Bt^T + bias, optional GELU, bf16 out.
// Same XOR swizzle as qkv.
// ---------------------------------------------------------------------------
__global__ __launch_bounds__(256) void gemm_mfma_kernel(
        const unsigned short* __restrict__ A,
        const unsigned short* __restrict__ Bt,
        const float* __restrict__ bias,
        unsigned short* __restrict__ Cb,
        int M, int K, int N, int act) {
    __shared__ unsigned short As[128 * 32];
    __shared__ unsigned short Bs[128 * 32];
    int tid = threadIdx.x;
    int wave = tid >> 6, lane = tid & 63;
    int rowBase = blockIdx.y * 128, colBase = blockIdx.x * 128;
    int m0w = (wave & 1) * 64, n0w = (wave >> 1) * 64;
    int lr = lane & 15, quad = lane >> 4;
    int qx = quad ^ (lr & 3);

    floatx4 acc[4][4];
#pragma unroll
    for (int mi = 0; mi < 4; mi++)
#pragma unroll
        for (int nj = 0; nj < 4; nj++) acc[mi][nj] = (floatx4)0.0f;

    for (int kt = 0; kt < K; kt += 32) {
#pragma unroll
        for (int t = 0; t < 2; t++) {
            int idx = t * 256 + tid;
            int row = idx >> 2, kv8 = ((idx ^ row) & 3) * 8;
            async_ld16(A + (size_t)(rowBase + row) * K + kt + kv8, &As[idx * 8]);
            async_ld16(Bt + (size_t)(colBase + row) * K + kt + kv8, &Bs[idx * 8]);
        }
        __syncthreads();
        bf16x8 af[4], bfr[4];
#pragma unroll
        for (int mi = 0; mi < 4; mi++)
            af[mi] = *(const bf16x8*)&As[(m0w + mi * 16 + lr) * 32 + qx * 8];
#pragma unroll
        for (int nj = 0; nj < 4; nj++)
            bfr[nj] = *(const bf16x8*)&Bs[(n0w + nj * 16 + lr) * 32 + qx * 8];
#pragma unroll
        for (int mi = 0; mi < 4; mi++)
#pragma unroll
            for (int nj = 0; nj < 4; nj++)
                acc[mi][nj] = __builtin_amdgcn_mfma_f32_16x16x32_bf16(
                    af[mi], bfr[nj], acc[mi][nj], 0, 0, 0);
        __syncthreads();
    }

#pragma unroll
    for (int mi = 0; mi < 4; mi++) {
#pragma unroll
        for (int r = 0; r < 4; r++) {
            int grow = rowBase + m0w + mi * 16 + quad * 4 + r;
#pragma unroll
            for (int nj = 0; nj < 4; nj++) {
                int gcol = colBase + n0w + nj * 16 + lr;
                float c = acc[mi][nj][r] + bias[gcol];
                if (act) c = gelu_f(c);
                Cb[(size_t)grow * N + gcol] = f2bf(c);
            }
        }
    }
}

// ---------------------------------------------------------------------------
// Fused Wo-GEMM + bias + residual + LayerNorm. 16 rows x 256 cols, 1 wave.
// XOR swizzle on As/Bs.
// ---------------------------------------------------------------------------
__global__ __launch_bounds__(64) void wo_ln_kernel(
        const unsigned short* __restrict__ A,     // ab_b [8192][256]
        const unsigned short* __restrict__ Bt,    // woT [256][256]
        const float* __restrict__ bias,
        const float* __restrict__ g, const float* __restrict__ be,
        float* __restrict__ xf, unsigned short* __restrict__ xb) {
    __shared__ unsigned short As[16 * 32];
    __shared__ unsigned short Bs[256 * 32];
    int tid = threadIdx.x;
    int l16 = tid & 15, quad = tid >> 4;
    int rowBase = blockIdx.x * 16;
    int qx = quad ^ (l16 & 3);

    floatx4 acc[16];
#pragma unroll
    for (int t = 0; t < 16; t++) acc[t] = (floatx4)0.0f;

    for (int kt = 0; kt < 256; kt += 32) {
        {
            int row = tid >> 2, kv8 = ((tid ^ row) & 3) * 8;
            async_ld16(A + (size_t)(rowBase + row) * 256 + kt + kv8, &As[tid * 8]);
        }
#pragma unroll
        for (int t = 0; t < 16; t++) {
            int idx = t * 64 + tid;
            int row = idx >> 2, kv8 = ((idx ^ row) & 3) * 8;
            async_ld16(Bt + (size_t)row * 256 + kt + kv8, &Bs[idx * 8]);
        }
        __syncthreads();
        bf16x8 af = *(const bf16x8*)&As[l16 * 32 + qx * 8];
#pragma unroll
        for (int t = 0; t < 16; t++) {
            bf16x8 bfr = *(const bf16x8*)&Bs[(t * 16 + l16) * 32 + qx * 8];
            acc[t] = __builtin_amdgcn_mfma_f32_16x16x32_bf16(af, bfr, acc[t], 0, 0, 0);
        }
        __syncthreads();
    }

    float bcol[16], gc[16], bec[16];
#pragma unroll
    for (int t = 0; t < 16; t++) {
        int c = t * 16 + l16;
        bcol[t] = bias[c]; gc[t] = g[c]; bec[t] = be[c];
    }
#pragma unroll
    for (int r = 0; r < 4; r++) {
        int grow = rowBase + quad * 4 + r;
        float v[16], s = 0.f, s2 = 0.f;
#pragma unroll
        for (int t = 0; t < 16; t++) {
            int c = t * 16 + l16;
            float val = acc[t][r] + bcol[t] + xf[(size_t)grow * 256 + c];
            v[t] = val; s += val; s2 += val * val;
        }
#pragma unroll
        for (int off = 1; off <= 8; off <<= 1) {
            s += __shfl_xor(s, off);
            s2 += __shfl_xor(s2, off);
        }
        float mean = s * (1.f / 256.f);
        float var = s2 * (1.f / 256.f) - mean * mean;
        float rstd = rsqrtf(var + 1e-5f);
#pragma unroll
        for (int t = 0; t < 16; t++) {
            int c = t * 16 + l16;
            float o = (v[t] - mean) * rstd * gc[t] + bec[t];
            xf[(size_t)grow * 256 + c] = o;
            xb[(size_t)grow * 256 + c] = f2bf(o);
        }
    }
}

// ---------------------------------------------------------------------------
// Fused FFN2(grouped) + bias + residual + LayerNorm. 64 rows x 128 cols.
// XOR swizzle on As/Bs.
// ---------------------------------------------------------------------------
__global__ __launch_bounds__(128) void ffn2_ln_kernel(
        const unsigned short* __restrict__ A,     // h_b [16384][512]
        const unsigned short* __restrict__ Bt,    // w2T [128][512]
        const float* __restrict__ bias,           // [128]
        const float* __restrict__ g, const float* __restrict__ be,
        float* __restrict__ xf, unsigned short* __restrict__ xb) {
    __shared__ unsigned short As[64 * 32];
    __shared__ unsigned short Bs[128 * 32];
    __shared__ float redS[64][2], redQ[64][2];
    int tid = threadIdx.x;
    int wave = tid >> 6, lane = tid & 63, l16 = lane & 15, quad = lane >> 4;
    int rowBase = blockIdx.x * 64;
    int n0w = wave * 64;
    int qx = quad ^ (l16 & 3);

    floatx4 acc[4][4];
#pragma unroll
    for (int mi = 0; mi < 4; mi++)
#pragma unroll
        for (int nj = 0; nj < 4; nj++) acc[mi][nj] = (floatx4)0.0f;

    for (int kt = 0; kt < 512; kt += 32) {
#pragma unroll
        for (int t = 0; t < 2; t++) {
            int idx = t * 128 + tid;
            int row = idx >> 2, kv8 = ((idx ^ row) & 3) * 8;
            async_ld16(A + (size_t)(rowBase + row) * 512 + kt + kv8, &As[idx * 8]);
        }
#pragma unroll
        for (int t = 0; t < 4; t++) {
            int idx = t * 128 + tid;
            int row = idx >> 2, kv8 = ((idx ^ row) & 3) * 8;
            async_ld16(Bt + (size_t)row * 512 + kt + kv8, &Bs[idx * 8]);
        }
        __syncthreads();
        bf16x8 af[4], bfr[4];
#pragma unroll
        for (int mi = 0; mi < 4; mi++)
            af[mi] = *(const bf16x8*)&As[(mi * 16 + l16) * 32 + qx * 8];
#pragma unroll
        for (int nj = 0; nj < 4; nj++)
            bfr[nj] = *(const bf16x8*)&Bs[(n0w + nj * 16 + l16) * 32 + qx * 8];
#pragma unroll
        for (int mi = 0; mi < 4; mi++)
#pragma unroll
            for (int nj = 0; nj < 4; nj++)
                acc[mi][nj] = __builtin_amdgcn_mfma_f32_16x16x32_bf16(
                    af[mi], bfr[nj], acc[mi][nj], 0, 0, 0);
        __syncthreads();
    }

#pragma unroll
    for (int mi = 0; mi < 4; mi++) {
#pragma unroll
        for (int r = 0; r < 4; r++) {
            int row = mi * 16 + quad * 4 + r;       // 0..63
            int grow = rowBase + row;
            int token = grow >> 1, dbase = (grow & 1) * 128;
            float s = 0.f, s2 = 0.f;
#pragma unroll
            for (int nj = 0; nj < 4; nj++) {
                int gcol = n0w + nj * 16 + l16;
                float val = acc[mi][nj][r] + bias[gcol]
                          + xf[(size_t)token * 256 + dbase + gcol];
                acc[mi][nj][r] = val;
                s += val; s2 += val * val;
            }
#pragma unroll
            for (int off = 1; off <= 8; off <<= 1) {
                s += __shfl_xor(s, off);
                s2 += __shfl_xor(s2, off);
            }
            if (l16 == 0) { redS[row][wave] = s; redQ[row][wave] = s2; }
        }
    }
    __syncthreads();

#pragma unroll
    for (int mi = 0; mi < 4; mi++) {
#pragma unroll
        for (int r = 0; r < 4; r++) {
            int row = mi * 16 + quad * 4 + r;
            int grow = rowBase + row;
            int token = grow >> 1, dbase = (grow & 1) * 128;
            float ts = redS[row][0] + redS[row][1] + redS[row ^ 1][0] + redS[row ^ 1][1];
            float tq = redQ[row][0] + redQ[row][1] + redQ[row ^ 1][0] + redQ[row ^ 1][1];
            float mean = ts * (1.f / 256.f);
            float var = tq * (1.f / 256.f) - mean * mean;
            float rstd = rsqrtf(var + 1e-5f);
#pragma unroll
            for (int nj = 0; nj < 4; nj++) {
                int gcol = n0w + nj * 16 + l16;
                int d = dbase + gcol;
                float o = (acc[mi][nj][r] - mean) * rstd * g[d] + be[d];
                xf[(size_t)token * 256 + d] = o;
                xb[(size_t)token * 256 + d] = f2bf(o);
            }
        }
    }
}

// ---------------------------------------------------------------------------
// MFMA attention. Grid = 1024 blocks, XCD-local decode (qg in high bits).
// K read directly from global (L2-hot), REGISTER-PREFETCHED one iteration
// ahead so the L2 latency hides under softmax+PV (the per-iter sched_barrier
// blocks compiler hoisting, so the prefetch must be explicit program-order).
// V staged via global_load_lds into Vs[db][k*16+d], consumed with
// ds_read_b64_tr_b16, pipelined one iteration ahead.
// ---------------------------------------------------------------------------
__global__ __launch_bounds__(256, 4) void attn_mfma_kernel(
        const unsigned short* __restrict__ q, const unsigned short* __restrict__ k,
        const unsigned short* __restrict__ v, unsigned short* __restrict__ o,
        const unsigned* __restrict__ mbits_g, int use_mask) {
    int bid = blockIdx.x;
    int qg = bid >> 7;          // 0..7
    int bh = bid & 127;         // XCD = bh & 7 = h
    int h = bh & 7, b = bh >> 3;
    int tid = threadIdx.x;

    __shared__ unsigned short Vs[2][NSEQ * 16];     // 32KB  [db][k*16+d]

    const unsigned short* kbase = k + (size_t)(b * 8 + h) * (NSEQ * DK);
    const unsigned short* vbase = v + (size_t)(b * 8 + h) * (NSEQ * DK);

    // V split: chunk c (16B) of Vs[db] covers k=c>>1, d = db*16 + (c&1)*8 .. +7
#pragma unroll
    for (int db = 0; db < 2; db++) {
#pragma unroll
        for (int t = 0; t < 4; t++) {
            int c = t * 256 + tid;                  // 0..1023
            int kk = c >> 1, half = c & 1;
            async_ld16(vbase + (size_t)kk * 32 + db * 16 + half * 8,
                       &Vs[db][c * 8]);
        }
    }

    int wave = tid >> 6, lane = tid & 63, l16 = lane & 15, quad = lane >> 4;
    int qbase = qg * 64 + wave * 16;

    bf16x8 qf = *(const bf16x8*)(q + ((size_t)(b * 8 + h) * NSEQ + qbase + l16) * 32 + quad * 8);

    unsigned mw[16];
    if (use_mask) {
        const uint4* mr = (const uint4*)(mbits_g + (size_t)(qbase + l16) * 16);
#pragma unroll
        for (int w = 0; w < 4; w++) *(uint4*)&mw[w * 4] = mr[w];
    } else {
#pragma unroll
        for (int w = 0; w < 16; w++) mw[w] = 0;
    }
    __syncthreads();

    unsigned va0 = (unsigned)(size_t)&Vs[0][0] + (unsigned)(lane * 8);
    unsigned va1 = (unsigned)(size_t)&Vs[1][0] + (unsigned)(lane * 8);

    // K fragment base: row r -> 16B at kfrag + r*32 elems
    const unsigned short* kfrag = kbase + (size_t)l16 * DK + quad * 8;

    floatx4 oT0 = (floatx4)0.f, oT1 = (floatx4)0.f;
    float m_run = -INFINITY, l_part = 0.f;

    uint32x2 t00, t01, t10, t11;
#define TR_ISSUE(cc)                                                      \
    asm volatile("ds_read_b64_tr_b16 %0, %4\n\t"                          \
                 "ds_read_b64_tr_b16 %1, %4 offset:512\n\t"               \
                 "ds_read_b64_tr_b16 %2, %5\n\t"                          \
                 "ds_read_b64_tr_b16 %3, %5 offset:512"                   \
                 : "=&v"(t00), "=&v"(t01), "=&v"(t10), "=&v"(t11)         \
                 : "v"(va0 + (unsigned)((cc) * 1024)),                    \
                   "v"(va1 + (unsigned)((cc) * 1024)))
    TR_ISSUE(0);

    bf16x8 k0 = *(const bf16x8*)(kfrag);
    bf16x8 k1 = *(const bf16x8*)(kfrag + 16 * DK);

#pragma unroll
    for (int c = 0; c < 16; c++) {
        floatx4 s0 = __builtin_amdgcn_mfma_f32_16x16x32_bf16(k0, qf, (floatx4)0.f, 0, 0, 0);
        floatx4 s1 = __builtin_amdgcn_mfma_f32_16x16x32_bf16(k1, qf, (floatx4)0.f, 0, 0, 0);

        // prefetch next iteration's K fragments NOW (program-order before the
        // sched_barrier below) so their L2 latency hides under softmax+PV.
        bf16x8 k0n, k1n;
        if (c < 15) {
            k0n = *(const bf16x8*)(kfrag + (size_t)((c + 1) * 32) * DK);
            k1n = *(const bf16x8*)(kfrag + (size_t)((c + 1) * 32 + 16) * DK);
        }

        float sv[8];
#pragma unroll
        for (int r = 0; r < 4; r++) { sv[r] = s0[r]; sv[4 + r] = s1[r]; }
        if (use_mask) {
            unsigned wb = mw[c];
#pragma unroll
            for (int r = 0; r < 4; r++) {
                if ((wb >> (quad * 4 + r)) & 1) sv[r] = -INFINITY;
                if ((wb >> (16 + quad * 4 + r)) & 1) sv[4 + r] = -INFINITY;
            }
        }
        float mx = fmaxf(fmaxf(fmaxf(sv[0], sv[1]), fmaxf(sv[2], sv[3])),
                         fmaxf(fmaxf(sv[4], sv[5]), fmaxf(sv[6], sv[7])));
        mx = fmaxf(mx, __shfl_xor(mx, 16));
        mx = fmaxf(mx, __shfl_xor(mx, 32));
        // wave-uniform exact skip: if no lane's block-max exceeds the running
        // max, mnew == m_run for every lane and the rescale is a no-op.
        if (!__all(mx <= m_run)) {
            float mnew = fmaxf(m_run, mx);
            float corr = (m_run == mnew) ? 1.f : __expf(m_run - mnew);
            l_part *= corr;
            oT0 *= corr; oT1 *= corr;
            m_run = mnew;
        }
        float p[8];
#pragma unroll
        for (int j = 0; j < 8; j++) {
            float e = __expf(sv[j] - m_run);
            p[j] = (sv[j] > -INFINITY) ? e : 0.f;
            l_part += p[j];
        }
        union { bf16x8 v8; unsigned u[4]; } pf;
#pragma unroll
        for (int j = 0; j < 4; j++)
            asm("v_cvt_pk_bf16_f32 %0, %1, %2"
                : "=v"(pf.u[j]) : "v"(p[2 * j]), "v"(p[2 * j + 1]));

        // consume tr(c); issue tr(c+1) after the PV MFMAs so its DS latency
        // hides under the next iteration's QK^T + softmax.
        asm volatile("s_waitcnt lgkmcnt(0)");
        __builtin_amdgcn_sched_barrier(0);
        union { bf16x8 v8; uint32x2 u[2]; } av0, av1;
        av0.u[0] = t00; av0.u[1] = t01;
        av1.u[0] = t10; av1.u[1] = t11;

        oT0 = __builtin_amdgcn_mfma_f32_16x16x32_bf16(av0.v8, pf.v8, oT0, 0, 0, 0);
        oT1 = __builtin_amdgcn_mfma_f32_16x16x32_bf16(av1.v8, pf.v8, oT1, 0, 0, 0);
        if (c < 15) TR_ISSUE(c + 1);
        k0 = k0n; k1 = k1n;
    }
#undef TR_ISSUE

    float l = l_part;
    l += __shfl_xor(l, 16);
    l += __shfl_xor(l, 32);
    float invl = (l > 0.f) ? 1.f / l : 0.f;

    unsigned short* orow = o + ((size_t)(b * NSEQ + qbase + l16)) * DMODEL + h * DK;
#pragma unroll
    for (int r = 0; r < 4; r++) {
        orow[quad * 4 + r]      = f2bf(oT0[r] * invl);
        orow[16 + quad * 4 + r] = f2bf(oT1[r] * invl);
    }
}

// Final LN: out = LayerNorm(x) * gf + bf (fp32)
__global__ __launch_bounds__(256) void final_ln_kernel(
        const float* __restrict__ a,
        const float* __restrict__ g, const float* __restrict__ be,
        float* __restrict__ out) {
    int t = blockIdx.x;
    int d = threadIdx.x;
    size_t idx = (size_t)t * DMODEL + d;
    float v = a[idx];
    float s = v, s2 = v * v;
#pragma unroll
    for (int off = 32; off; off >>= 1) {
        s  += __shfl_xor(s, off);
        s2 += __shfl_xor(s2, off);
    }
    __shared__ float ws1[4], ws2[4];
    int wid = d >> 6;
    if ((d & 63) == 0) { ws1[wid] = s; ws2[wid] = s2; }
    __syncthreads();
    s  = ws1[0] + ws1[1] + ws1[2] + ws1[3];
    s2 = ws2[0] + ws2[1] + ws2[2] + ws2[3];
    float mean = s * (1.f / DMODEL);
    float var = s2 * (1.f / DMODEL) - mean * mean;
    float rstd = rsqrtf(var + 1e-5f);
    out[idx] = (v - mean) * rstd * g[d] + be[d];
}

// ---------------------------------------------------------------------------
extern "C" void kernel_launch(void* const* d_in, const int* in_sizes, int n_in,
                              void* d_out, int out_size, void* d_ws, size_t ws_size,
                              hipStream_t stream) {
    const float* input  = (const float*)d_in[0];
    const float* inputv = (const float*)d_in[1];
    const float* pos    = (const float*)d_in[2];
    const float* Wq = (const float*)d_in[3];
    const float* bq = (const float*)d_in[4];
    const float* Wk = (const float*)d_in[5];
    const float* bk = (const float*)d_in[6];
    const float* Wv = (const float*)d_in[7];
    const float* bv = (const float*)d_in[8];
    const float* Wo = (const float*)d_in[9];
    const float* bo = (const float*)d_in[10];
    const float* W1 = (const float*)d_in[11];
    const float* b1 = (const float*)d_in[12];
    const float* W2 = (const float*)d_in[13];
    const float* b2 = (const float*)d_in[14];
    const float* g1 = (const float*)d_in[15];
    const float* be1 = (const float*)d_in[16];
    const float* g2 = (const float*)d_in[17];
    const float* be2 = (const float*)d_in[18];
    const float* gf = (const float*)d_in[19];
    const float* bff = (const float*)d_in[20];
    const int* mask = (const int*)d_in[21];

    float* out = (float*)d_out;

    // Workspace layout (bytes), ~37 MB
    char* wsb = (char*)d_ws;
    float* x_f  = (float*)(wsb + ((size_t)0 << 20));                    // 8 MB
    unsigned short* x_b  = (unsigned short*)(wsb + ((size_t)8 << 20));  // 4 MB
    unsigned short* xv_b = (unsigned short*)(wsb + ((size_t)12 << 20)); // 4 MB
    unsigned short* qb_b = (unsigned short*)(wsb + ((size_t)16 << 20)); // 4 MB
    unsigned short* kb_b = (unsigned short*)(wsb + ((size_t)20 << 20)); // 4 MB
    unsigned short* vb_b = (unsigned short*)(wsb + ((size_t)24 << 20)); // 4 MB
    unsigned short* ab_b = (unsigned short*)(wsb + ((size_t)28 << 20)); // 4 MB
    unsigned short* h_b  = qb_b;  // 16 MB alias over qb..ab (dead during FFN)
    unsigned short* wqT = (unsigned short*)(wsb + ((size_t)32 << 20));
    unsigned short* wkT = wqT + (size_t)4 * 65536;
    unsigned short* wvT = wkT + (size_t)4 * 65536;
    unsigned short* woT = wvT + (size_t)4 * 65536;
    unsigned short* w1T = woT + (size_t)4 * 65536;   // 4 x 262144
    unsigned short* w2T = w1T + (size_t)4 * 262144;  // 4 x 65536
    unsigned* mbits = (unsigned*)(wsb + ((size_t)37 << 20));            // 32 KB

    const size_t TOK = (size_t)BN * DMODEL;

    // --- preconversions (2 dispatches) ---
    conv_all_kernel<<<9248, 256, 0, stream>>>(Wq, Wk, Wv, Wo, W1, W2, mask,
                                              wqT, wkT, wvT, woT, w1T, w2T, mbits);
    add_pos_kernel<<<(int)((TOK + 255) / 256), 256, 0, stream>>>(
        input, inputv, pos, x_f, x_b, xv_b, (int)TOK);

    for (int i = 0; i < NLAYER; i++) {
        const unsigned short* WqT_i = wqT + (size_t)i * 65536;
        const unsigned short* WkT_i = wkT + (size_t)i * 65536;
        const unsigned short* WvT_i = wvT + (size_t)i * 65536;
        const unsigned short* WoT_i = woT + (size_t)i * 65536;
        const unsigned short* W1T_i = w1T + (size_t)i * 262144;
        const unsigned short* W2T_i = w2T + (size_t)i * 65536;

        qkv_mfma_kernel<<<dim3(6, 64), 256, 0, stream>>>(
            x_b, xv_b, WqT_i, WkT_i, WvT_i,
            bq + i * DMODEL, bk + i * DMODEL, bv + i * DMODEL,
            qb_b, kb_b, vb_b);

        attn_mfma_kernel<<<BDIM * NHEAD * 8, 256, 0, stream>>>(
            qb_b, kb_b, vb_b, ab_b, mbits, (i & 1));

        wo_ln_kernel<<<BN / 16, 64, 0, stream>>>(
            ab_b, WoT_i, bo + i * DMODEL,
            g1 + i * DMODEL, be1 + i * DMODEL, x_f, x_b);

        gemm_mfma_kernel<<<dim3(8, 64), 256, 0, stream>>>(
            x_b, W1T_i, b1 + i * DFF, h_b, BN, DMODEL, DFF, 1);

        ffn2_ln_kernel<<<(2 * BN) / 64, 128, 0, stream>>>(
            h_b, W2T_i, b2 + i * (DMODEL / 2),
            g2 + i * DMODEL, be2 + i * DMODEL, x_f, x_b);
    }

    final_ln_kernel<<<BN, DMODEL, 0, stream>>>(x_f, gf, bff, out);
}